// Round 1
// baseline (252.844 us; speedup 1.0000x reference)
//
#include <hip/hip_runtime.h>

// Problem dims (fixed by reference)
#define BATCH  4096
#define IN_DIM 256
#define HID    512
#define STATES 16
#define NCOL   (HID * STATES)   // 8192

// Tiling
#define BM 64
#define BN 64
#define BK 32

__global__ __launch_bounds__(256) void mqc_fused_kernel(
    const float* __restrict__ x,        // [BATCH, IN_DIM]
    const float* __restrict__ hq,       // [BATCH, NCOL]
    const float* __restrict__ W,        // [IN_DIM, NCOL]
    float* __restrict__ out_mean,       // [BATCH, HID]
    float* __restrict__ out_new)        // [BATCH, NCOL]
{
    __shared__ float As[BK][BM];   // x tile, transposed: As[k][m]
    __shared__ float Bs[BK][BN];   // W tile: Bs[k][n]

    const int t    = threadIdx.x;
    const int row0 = blockIdx.x * BM;   // batch tile origin
    const int col0 = blockIdx.y * BN;   // n tile origin

    // per-thread 4x4 register tile
    const int tm = (t >> 4) * 4;        // 0..60
    const int tn = (t & 15) * 4;        // 0..60

    float acc[4][4] = {};

    for (int kt = 0; kt < IN_DIM / BK; ++kt) {
        // --- stage A tile (BM x BK), store transposed into As[k][m] ---
        // 64 rows x 32 cols = 512 float4; 2 per thread
        #pragma unroll
        for (int j = 0; j < 2; ++j) {
            int f  = t * 2 + j;
            int r  = f >> 3;        // 0..63  (8 float4 per row)
            int c4 = f & 7;         // 0..7
            const float4 v = *(const float4*)(&x[(size_t)(row0 + r) * IN_DIM + kt * BK + c4 * 4]);
            As[c4 * 4 + 0][r] = v.x;
            As[c4 * 4 + 1][r] = v.y;
            As[c4 * 4 + 2][r] = v.z;
            As[c4 * 4 + 3][r] = v.w;
        }
        // --- stage B tile (BK x BN) ---
        // 32 rows x 64 cols = 512 float4; 2 per thread
        #pragma unroll
        for (int j = 0; j < 2; ++j) {
            int f  = t * 2 + j;
            int r  = f >> 4;        // 0..31  (16 float4 per row)
            int c4 = f & 15;        // 0..15
            const float4 v = *(const float4*)(&W[(size_t)(kt * BK + r) * NCOL + col0 + c4 * 4]);
            *(float4*)(&Bs[r][c4 * 4]) = v;
        }
        __syncthreads();

        // --- inner product over this K tile ---
        #pragma unroll
        for (int k = 0; k < BK; ++k) {
            const float4 a = *(const float4*)(&As[k][tm]);
            const float4 b = *(const float4*)(&Bs[k][tn]);
            const float av[4] = {a.x, a.y, a.z, a.w};
            const float bv[4] = {b.x, b.y, b.z, b.w};
            #pragma unroll
            for (int mi = 0; mi < 4; ++mi)
                #pragma unroll
                for (int ni = 0; ni < 4; ++ni)
                    acc[mi][ni] = fmaf(av[mi], bv[ni], acc[mi][ni]);
        }
        __syncthreads();
    }

    // --- fused epilogue: tanh(C + 0.9*h), write new state, s-group mean ---
    #pragma unroll
    for (int mi = 0; mi < 4; ++mi) {
        const int b = row0 + tm + mi;
        const int n = col0 + tn;
        const float4 hv = *(const float4*)(&hq[(size_t)b * NCOL + n]);
        float nv[4];
        nv[0] = tanhf(acc[mi][0] + 0.9f * hv.x);
        nv[1] = tanhf(acc[mi][1] + 0.9f * hv.y);
        nv[2] = tanhf(acc[mi][2] + 0.9f * hv.z);
        nv[3] = tanhf(acc[mi][3] + 0.9f * hv.w);
        *(float4*)(&out_new[(size_t)b * NCOL + n]) = *(const float4*)nv;

        // mean over the 16-wide s group: this thread holds 4 of the 16;
        // aligned 4-lane groups (lane&~3) hold the same (b, h) group.
        float s = nv[0] + nv[1] + nv[2] + nv[3];
        s += __shfl_xor(s, 1);
        s += __shfl_xor(s, 2);
        if ((t & 3) == 0) {
            out_mean[(size_t)b * HID + (n >> 4)] = s * (1.0f / 16.0f);
        }
    }
}

extern "C" void kernel_launch(void* const* d_in, const int* in_sizes, int n_in,
                              void* d_out, int out_size, void* d_ws, size_t ws_size,
                              hipStream_t stream) {
    const float* x  = (const float*)d_in[0];   // [4096, 256]
    const float* hq = (const float*)d_in[1];   // [4096, 512, 16]
    const float* W  = (const float*)d_in[2];   // [256, 512, 16]

    float* out_mean = (float*)d_out;                          // [4096, 512]
    float* out_new  = (float*)d_out + (size_t)BATCH * HID;    // [4096, 512, 16]

    dim3 grid(BATCH / BM, NCOL / BN);   // (64, 128)
    dim3 block(256);
    mqc_fused_kernel<<<grid, block, 0, stream>>>(x, hq, W, out_mean, out_new);
}